// Round 4
// baseline (413.189 us; speedup 1.0000x reference)
//
#include <hip/hip_runtime.h>
#include <stdint.h>

typedef unsigned short u16;
typedef __attribute__((ext_vector_type(8))) short short8;
typedef __attribute__((ext_vector_type(4))) float f32x4;

#define AS1 __attribute__((address_space(1)))
#define AS3 __attribute__((address_space(3)))

static __device__ __forceinline__ void gload_lds16(const void* g, void* l) {
  __builtin_amdgcn_global_load_lds((const AS1 void*)g, (AS3 void*)l, 16, 0, 0);
}

static __device__ __forceinline__ u16 bf16r(float f) {
  union { float f; uint32_t u; } c; c.f = f;
  uint32_t u = c.u;
  u += 0x7fffu + ((u >> 16) & 1u);
  return (u16)(u >> 16);
}

static constexpr int NB = 16, CIN = 256, COUT = 256, HW = 128, SDIM = 512;
static constexpr float SCALE = 1.0f / 48.0f;   // 1/sqrt(Cin*3*3)

// ---------------- K1: s[b][ci] = style[b,:] @ mod_w[ci,:] + mod_b[ci] ----------------
__global__ void k_style(const float* __restrict__ style, const float* __restrict__ mod_w,
                        const float* __restrict__ mod_b, float* __restrict__ s) {
  int b = blockIdx.x, ci = threadIdx.x;
  const float4* st = (const float4*)(style + (size_t)b * SDIM);
  const float4* mw = (const float4*)(mod_w + (size_t)ci * SDIM);
  float acc = 0.f;
  #pragma unroll 4
  for (int j = 0; j < SDIM / 4; ++j) {
    float4 a = st[j], w = mw[j];
    acc += a.x * w.x + a.y * w.y + a.z * w.z + a.w * w.w;
  }
  s[b * CIN + ci] = acc + mod_b[ci];
}

// ---------------- K2: modulated+demodulated weights -> bf16 Wb[b][kpos][co][ci] ------
__global__ void k_wmod(const float* __restrict__ weight, const float* __restrict__ s,
                       u16* __restrict__ Wb) {
  __shared__ float wld[CIN * 9];
  __shared__ float red[8];
  int bid = blockIdx.x;
  int b = bid >> 8, co = bid & 255;
  int t = threadIdx.x;
  const float* wsrc = weight + (size_t)co * (CIN * 9);
  for (int i = t; i < CIN * 9; i += 256) wld[i] = wsrc[i];
  __syncthreads();
  int ci = t;
  float sv = s[b * CIN + ci];
  float v[9];
  float sq = 0.f;
  #pragma unroll
  for (int k = 0; k < 9; ++k) {
    float w = SCALE * wld[ci * 9 + k] * sv;
    v[k] = w;
    sq += w * w;
  }
  #pragma unroll
  for (int off = 32; off; off >>= 1) sq += __shfl_down(sq, off);
  int lane = t & 63, wid = t >> 6;
  if (lane == 0) red[wid] = sq;
  __syncthreads();
  if (t == 0) red[4] = rsqrtf(red[0] + red[1] + red[2] + red[3] + 1e-8f);
  __syncthreads();
  float demod = red[4];
  #pragma unroll
  for (int k = 0; k < 9; ++k) {
    Wb[(((size_t)b * 9 + k) * COUT + co) * CIN + ci] = bf16r(v[k] * demod);
  }
}

// ---------------- K3: x fp32 [b][ci][h][w] -> bf16 transposed padded -----------------
// xTp[b][hh][pxp][ci]: hh in [0,130) = image row h+1 (hh=0 and hh=129 are zero guard
// rows); pxp in [0,130): pxp==0 and pxp==129 are zero pad columns, pxp=1+w.
__global__ void k_xt(const float* __restrict__ x, u16* __restrict__ xTp) {
  __shared__ u16 T[128 * 65];
  int bid = blockIdx.x;
  int b = bid >> 7, h = bid & 127;
  int t = threadIdx.x;
  size_t rowbase = ((size_t)b * 130 + (h + 1)) * 130 * CIN;
  // zero pad columns
  xTp[rowbase + t] = 0;
  xTp[rowbase + (size_t)129 * CIN + t] = 0;
  // zero guard rows
  if (h == 0) {
    uint32_t* g = (uint32_t*)(xTp + (size_t)b * 130 * 130 * CIN);
    for (int i = t; i < 130 * CIN / 2; i += 256) g[i] = 0;
  }
  if (h == 127) {
    uint32_t* g = (uint32_t*)(xTp + ((size_t)b * 130 + 129) * 130 * CIN);
    for (int i = t; i < 130 * CIN / 2; i += 256) g[i] = 0;
  }
  for (int ci0 = 0; ci0 < CIN; ci0 += 64) {
    __syncthreads();
    #pragma unroll
    for (int i = 0; i < 8; ++i) {
      int idx = t + i * 256;
      int ci = idx >> 5, px4 = idx & 31;
      float4 v = *(const float4*)(x + (((size_t)b * CIN + ci0 + ci) * HW + h) * HW + px4 * 4);
      T[(px4 * 4 + 0) * 65 + ci] = bf16r(v.x);
      T[(px4 * 4 + 1) * 65 + ci] = bf16r(v.y);
      T[(px4 * 4 + 2) * 65 + ci] = bf16r(v.z);
      T[(px4 * 4 + 3) * 65 + ci] = bf16r(v.w);
    }
    __syncthreads();
    int ci = t & 63, pxo = t >> 6;
    #pragma unroll
    for (int i = 0; i < 32; ++i) {
      int px = i * 4 + pxo;
      xTp[rowbase + (size_t)(px + 1) * CIN + ci0 + ci] = T[px * 65 + ci];
    }
  }
}

// ---------------- K4: implicit GEMM conv, 256x256 tile, 2-phase kk-split dbuf -------
// block = (b, hp): out tile 256co x 256px (rows 2hp, 2hp+1). 8 waves 2Mx4N, wave out
// 128x64. K = 9 kpos x 256 ci = 36 K-tiles of 64. LDS 2 slots x (A 32KB + B 32KB).
// Per kt: 2 phases (one per K-half kk): 12 balanced ds_read_b128 + 4 gload_lds ->
// barrier -> 32 independent MFMA -> barrier. vmcnt(0) folded before last barrier.
static constexpr int SLOTU = 32768;  // u16 per slot

__global__ __launch_bounds__(512, 1) void k_conv(const u16* __restrict__ Wb,
                                                 const u16* __restrict__ xTp,
                                                 const float* __restrict__ bias,
                                                 float* __restrict__ out) {
  extern __shared__ u16 lds[];
  int bid = blockIdx.x;
  // T1: bijective XCD swizzle (nwg=1024, 1024%8==0)
  int swz = (bid & 7) * 128 + (bid >> 3);
  int b = swz >> 6, hp = swz & 63;
  int h0 = hp * 2;

  int t = threadIdx.x, lane = t & 63, wid = t >> 6;
  int wr = wid >> 2, wc = wid & 3;
  int rowoff = wid * 8 + (lane >> 3);               // staging row within 64-row unit
  int swzc = ((lane & 7) ^ (lane >> 3)) << 3;       // pre-swizzled source col (u16)
  int cxor = (lane & 7) << 3;                       // read-side XOR (row&7 == lane&7)
  int klo = (lane >> 4) << 3;
  int arow = (wr * 128 + (lane & 15)) * 64;         // + mt*1024
  int brow = (wc * 64 + (lane & 15)) * 64;          // + nt*1024
  const size_t wbB = (size_t)b * 9 * 65536;
  const size_t xB = (size_t)b * 130 * 130 * 256;

  f32x4 acc[8][4];
  #pragma unroll
  for (int i = 0; i < 8; ++i)
    #pragma unroll
    for (int j = 0; j < 4; ++j) acc[i][j] = (f32x4)0.f;

  // staging source addresses for K-tile kta, load index i in 0..3
  auto srcA = [&](int kta, int i) -> const u16* {
    int kpos = kta >> 2, ci0 = (kta & 3) << 6;
    return Wb + wbB + (size_t)kpos * 65536 + (size_t)(i * 64 + rowoff) * 256 + ci0 + swzc;
  };
  auto srcB = [&](int kta, int i) -> const u16* {
    int kpos = kta >> 2, ci0 = (kta & 3) << 6;
    int kh = kpos < 3 ? 0 : (kpos < 6 ? 1 : 2);
    int kw = kpos - kh * 3;
    int hh = h0 + kh + (i >> 1);                    // guard layout: image row = hh-1
    int pxp = kw + (i & 1) * 64 + rowoff;
    return xTp + xB + ((size_t)hh * 130 + pxp) * 256 + ci0 + swzc;
  };

  // prologue: stage kt=0 into slot 0
  {
    u16* A2 = lds;
    u16* B2 = lds + 16384;
    #pragma unroll
    for (int i = 0; i < 4; ++i) gload_lds16(srcA(0, i), A2 + (i * 64 + wid * 8) * 64);
    #pragma unroll
    for (int i = 0; i < 4; ++i) gload_lds16(srcB(0, i), B2 + (i * 64 + wid * 8) * 64);
  }
  asm volatile("s_waitcnt vmcnt(0)" ::: "memory");
  __builtin_amdgcn_s_barrier();
  asm volatile("" ::: "memory");

  for (int kt = 0; kt < 36; ++kt) {
    u16* Ac = lds + (kt & 1) * SLOTU;
    u16* Bc = Ac + 16384;
    u16* An = lds + ((kt & 1) ^ 1) * SLOTU;
    u16* Bn = An + 16384;
    bool pf = kt < 35;
    int kta = kt + 1;

    short8 af[8], bf[4];

#define LD_A(M, KK) (*(const short8*)&Ac[arow + (M) * 1024 + (((KK) * 32 + klo) ^ cxor)])
#define LD_B(N, KK) (*(const short8*)&Bc[brow + (N) * 1024 + (((KK) * 32 + klo) ^ cxor)])

    // -------- P0: kk=0 frags (8A + 4B reads); stage next A; 32 indep MFMA --------
    #pragma unroll
    for (int mt = 0; mt < 8; ++mt) af[mt] = LD_A(mt, 0);
    #pragma unroll
    for (int nt = 0; nt < 4; ++nt) bf[nt] = LD_B(nt, 0);
    if (pf) {
      #pragma unroll
      for (int i = 0; i < 4; ++i) gload_lds16(srcA(kta, i), An + (i * 64 + wid * 8) * 64);
    }
    asm volatile("" ::: "memory");
    __builtin_amdgcn_s_barrier();
    asm volatile("" ::: "memory");
    __builtin_amdgcn_s_setprio(1);
    #pragma unroll
    for (int mt = 0; mt < 8; ++mt)
      #pragma unroll
      for (int nt = 0; nt < 4; ++nt)
        acc[mt][nt] = __builtin_amdgcn_mfma_f32_16x16x32_bf16(af[mt], bf[nt], acc[mt][nt], 0, 0, 0);
    __builtin_amdgcn_s_setprio(0);
    asm volatile("" ::: "memory");
    __builtin_amdgcn_s_barrier();
    asm volatile("" ::: "memory");

    // -------- P1: kk=1 frags (8A + 4B reads); stage next B; 32 indep MFMA --------
    #pragma unroll
    for (int mt = 0; mt < 8; ++mt) af[mt] = LD_A(mt, 1);
    #pragma unroll
    for (int nt = 0; nt < 4; ++nt) bf[nt] = LD_B(nt, 1);
    if (pf) {
      #pragma unroll
      for (int i = 0; i < 4; ++i) gload_lds16(srcB(kta, i), Bn + (i * 64 + wid * 8) * 64);
    }
    asm volatile("" ::: "memory");
    __builtin_amdgcn_s_barrier();
    asm volatile("" ::: "memory");
    __builtin_amdgcn_s_setprio(1);
    #pragma unroll
    for (int mt = 0; mt < 8; ++mt)
      #pragma unroll
      for (int nt = 0; nt < 4; ++nt)
        acc[mt][nt] = __builtin_amdgcn_mfma_f32_16x16x32_bf16(af[mt], bf[nt], acc[mt][nt], 0, 0, 0);
    __builtin_amdgcn_s_setprio(0);
    // boundary: own stages must be drained; barrier publishes slot to all waves
    if (pf) asm volatile("s_waitcnt vmcnt(0)" ::: "memory");
    asm volatile("" ::: "memory");
    __builtin_amdgcn_s_barrier();
    asm volatile("" ::: "memory");
#undef LD_A
#undef LD_B
  }

  // -------- epilogue: C write --------
  #pragma unroll
  for (int mt = 0; mt < 8; ++mt) {
    #pragma unroll
    for (int j = 0; j < 4; ++j) {
      int co = wr * 128 + mt * 16 + ((lane >> 4) * 4) + j;
      float bv = bias[co];
      #pragma unroll
      for (int nt = 0; nt < 4; ++nt) {
        int px = wc * 64 + nt * 16 + (lane & 15);
        int h = h0 + (px >> 7), w = px & 127;
        out[(((size_t)b * COUT + co) * HW + h) * HW + w] = acc[mt][nt][j] + bv;
      }
    }
  }
}

extern "C" void kernel_launch(void* const* d_in, const int* in_sizes, int n_in,
                              void* d_out, int out_size, void* d_ws, size_t ws_size,
                              hipStream_t stream) {
  const float* x      = (const float*)d_in[0];
  const float* style  = (const float*)d_in[1];
  const float* weight = (const float*)d_in[2];
  const float* mod_w  = (const float*)d_in[3];
  const float* mod_b  = (const float*)d_in[4];
  const float* bias   = (const float*)d_in[5];
  float* out = (float*)d_out;

  char* ws = (char*)d_ws;
  float* s   = (float*)ws;                                           // 16 KB
  u16* Wb    = (u16*)(ws + 16384);                                   // 18.9 MB
  u16* xTp   = (u16*)(ws + 16384 + (size_t)NB * 9 * COUT * CIN * 2); // 138.4 MB

  (void)hipFuncSetAttribute((const void*)k_conv,
                            hipFuncAttributeMaxDynamicSharedMemorySize, 2 * SLOTU * 2);

  k_style<<<NB, 256, 0, stream>>>(style, mod_w, mod_b, s);
  k_wmod<<<NB * COUT, 256, 0, stream>>>(weight, s, Wb);
  k_xt<<<NB * HW, 256, 0, stream>>>(x, xTp);
  k_conv<<<NB * (HW / 2), 512, 2 * SLOTU * 2, stream>>>(Wb, xTp, bias, out);
}

// Round 5
// 408.767 us; speedup vs baseline: 1.0108x; 1.0108x over previous
//
#include <hip/hip_runtime.h>
#include <stdint.h>

typedef unsigned short u16;
typedef __attribute__((ext_vector_type(8))) short short8;
typedef __attribute__((ext_vector_type(4))) float f32x4;

#define AS1 __attribute__((address_space(1)))
#define AS3 __attribute__((address_space(3)))

static __device__ __forceinline__ void gload_lds16(const void* g, void* l) {
  __builtin_amdgcn_global_load_lds((const AS1 void*)g, (AS3 void*)l, 16, 0, 0);
}

static __device__ __forceinline__ u16 bf16r(float f) {
  union { float f; uint32_t u; } c; c.f = f;
  uint32_t u = c.u;
  u += 0x7fffu + ((u >> 16) & 1u);
  return (u16)(u >> 16);
}

static constexpr int NB = 16, CIN = 256, COUT = 256, HW = 128, SDIM = 512;
static constexpr float SCALE = 1.0f / 48.0f;   // 1/sqrt(Cin*3*3)

// ---------------- K1: s[b][ci] = style[b,:] @ mod_w[ci,:] + mod_b[ci] ----------------
__global__ void k_style(const float* __restrict__ style, const float* __restrict__ mod_w,
                        const float* __restrict__ mod_b, float* __restrict__ s) {
  int b = blockIdx.x, ci = threadIdx.x;
  const float4* st = (const float4*)(style + (size_t)b * SDIM);
  const float4* mw = (const float4*)(mod_w + (size_t)ci * SDIM);
  float acc = 0.f;
  #pragma unroll 4
  for (int j = 0; j < SDIM / 4; ++j) {
    float4 a = st[j], w = mw[j];
    acc += a.x * w.x + a.y * w.y + a.z * w.z + a.w * w.w;
  }
  s[b * CIN + ci] = acc + mod_b[ci];
}

// ---------------- K2: modulated+demodulated weights -> bf16 Wb[b][kpos][co][ci] ------
__global__ void k_wmod(const float* __restrict__ weight, const float* __restrict__ s,
                       u16* __restrict__ Wb) {
  __shared__ float wld[CIN * 9];
  __shared__ float red[8];
  int bid = blockIdx.x;
  int b = bid >> 8, co = bid & 255;
  int t = threadIdx.x;
  const float* wsrc = weight + (size_t)co * (CIN * 9);
  for (int i = t; i < CIN * 9; i += 256) wld[i] = wsrc[i];
  __syncthreads();
  int ci = t;
  float sv = s[b * CIN + ci];
  float v[9];
  float sq = 0.f;
  #pragma unroll
  for (int k = 0; k < 9; ++k) {
    float w = SCALE * wld[ci * 9 + k] * sv;
    v[k] = w;
    sq += w * w;
  }
  #pragma unroll
  for (int off = 32; off; off >>= 1) sq += __shfl_down(sq, off);
  int lane = t & 63, wid = t >> 6;
  if (lane == 0) red[wid] = sq;
  __syncthreads();
  if (t == 0) red[4] = rsqrtf(red[0] + red[1] + red[2] + red[3] + 1e-8f);
  __syncthreads();
  float demod = red[4];
  #pragma unroll
  for (int k = 0; k < 9; ++k) {
    Wb[(((size_t)b * 9 + k) * COUT + co) * CIN + ci] = bf16r(v[k] * demod);
  }
}

// ---------------- K3: x fp32 [b][ci][h][w] -> bf16 transposed padded -----------------
// xTp[b][hh][pxp][ci]: hh in [0,130) = image row h+1 (hh=0 and hh=129 are zero guard
// rows); pxp in [0,130): pxp==0 and pxp==129 are zero pad columns, pxp=1+w.
__global__ void k_xt(const float* __restrict__ x, u16* __restrict__ xTp) {
  __shared__ u16 T[128 * 65];
  int bid = blockIdx.x;
  int b = bid >> 7, h = bid & 127;
  int t = threadIdx.x;
  size_t rowbase = ((size_t)b * 130 + (h + 1)) * 130 * CIN;
  // zero pad columns
  xTp[rowbase + t] = 0;
  xTp[rowbase + (size_t)129 * CIN + t] = 0;
  // zero guard rows
  if (h == 0) {
    uint32_t* g = (uint32_t*)(xTp + (size_t)b * 130 * 130 * CIN);
    for (int i = t; i < 130 * CIN / 2; i += 256) g[i] = 0;
  }
  if (h == 127) {
    uint32_t* g = (uint32_t*)(xTp + ((size_t)b * 130 + 129) * 130 * CIN);
    for (int i = t; i < 130 * CIN / 2; i += 256) g[i] = 0;
  }
  for (int ci0 = 0; ci0 < CIN; ci0 += 64) {
    __syncthreads();
    #pragma unroll
    for (int i = 0; i < 8; ++i) {
      int idx = t + i * 256;
      int ci = idx >> 5, px4 = idx & 31;
      float4 v = *(const float4*)(x + (((size_t)b * CIN + ci0 + ci) * HW + h) * HW + px4 * 4);
      T[(px4 * 4 + 0) * 65 + ci] = bf16r(v.x);
      T[(px4 * 4 + 1) * 65 + ci] = bf16r(v.y);
      T[(px4 * 4 + 2) * 65 + ci] = bf16r(v.z);
      T[(px4 * 4 + 3) * 65 + ci] = bf16r(v.w);
    }
    __syncthreads();
    int ci = t & 63, pxo = t >> 6;
    #pragma unroll
    for (int i = 0; i < 32; ++i) {
      int px = i * 4 + pxo;
      xTp[rowbase + (size_t)(px + 1) * CIN + ci0 + ci] = T[px * 65 + ci];
    }
  }
}

// ---------------- K4: implicit GEMM conv, 256x256 tile, barrier-minimal dbuf --------
// block = (b, hp): out tile 256co x 256px (rows 2hp, 2hp+1). 8 waves 2Mx4N, wave out
// 128x64. K = 9 kpos x 256 ci = 36 K-tiles of 64. LDS 2 slots x (A 32KB + B 32KB).
// ONE __syncthreads per kt: within a kt the compiler freely interleaves 24 ds_reads,
// 8 gload_lds and 64 MFMAs (fine-grained lgkmcnt), so LDS and matrix pipes overlap.
static constexpr int SLOTU = 32768;  // u16 per slot

__global__ __launch_bounds__(512, 2) void k_conv(const u16* __restrict__ Wb,
                                                 const u16* __restrict__ xTp,
                                                 const float* __restrict__ bias,
                                                 float* __restrict__ out) {
  extern __shared__ u16 lds[];
  int bid = blockIdx.x;
  // T1: bijective XCD swizzle (nwg=1024, 1024%8==0)
  int swz = (bid & 7) * 128 + (bid >> 3);
  int b = swz >> 6, hp = swz & 63;
  int h0 = hp * 2;

  int t = threadIdx.x, lane = t & 63, wid = t >> 6;
  int wr = wid >> 2, wc = wid & 3;
  int rowoff = wid * 8 + (lane >> 3);               // staging row within 64-row unit
  int swzc = ((lane & 7) ^ (lane >> 3)) << 3;       // pre-swizzled source col (u16)
  int cxor = (lane & 7) << 3;                       // read-side XOR (row&7 == lane&7)
  int klo = (lane >> 4) << 3;
  int arow = (wr * 128 + (lane & 15)) * 64;         // + mt*1024
  int brow = (wc * 64 + (lane & 15)) * 64;          // + nt*1024
  const size_t wbB = (size_t)b * 9 * 65536;
  const size_t xB = (size_t)b * 130 * 130 * 256;

  f32x4 acc[8][4];
  #pragma unroll
  for (int i = 0; i < 8; ++i)
    #pragma unroll
    for (int j = 0; j < 4; ++j) acc[i][j] = (f32x4)0.f;

  // staging source addresses for K-tile kta, load index i in 0..3
  auto srcA = [&](int kta, int i) -> const u16* {
    int kpos = kta >> 2, ci0 = (kta & 3) << 6;
    return Wb + wbB + (size_t)kpos * 65536 + (size_t)(i * 64 + rowoff) * 256 + ci0 + swzc;
  };
  auto srcB = [&](int kta, int i) -> const u16* {
    int kpos = kta >> 2, ci0 = (kta & 3) << 6;
    int kh = kpos < 3 ? 0 : (kpos < 6 ? 1 : 2);
    int kw = kpos - kh * 3;
    int hh = h0 + kh + (i >> 1);                    // guard layout: image row = hh-1
    int pxp = kw + (i & 1) * 64 + rowoff;
    return xTp + xB + ((size_t)hh * 130 + pxp) * 256 + ci0 + swzc;
  };

  // prologue: stage kt=0 into slot 0
  {
    u16* A2 = lds;
    u16* B2 = lds + 16384;
    #pragma unroll
    for (int i = 0; i < 4; ++i) gload_lds16(srcA(0, i), A2 + (i * 64 + wid * 8) * 64);
    #pragma unroll
    for (int i = 0; i < 4; ++i) gload_lds16(srcB(0, i), B2 + (i * 64 + wid * 8) * 64);
  }
  __syncthreads();   // drains vmcnt + publishes slot 0

  for (int kt = 0; kt < 36; ++kt) {
    u16* Ac = lds + (kt & 1) * SLOTU;
    u16* Bc = Ac + 16384;
    u16* An = lds + ((kt & 1) ^ 1) * SLOTU;
    u16* Bn = An + 16384;
    bool pf = kt < 35;
    int kta = kt + 1;

#define LD_A(M, KK) (*(const short8*)&Ac[arow + (M) * 1024 + (((KK) * 32 + klo) ^ cxor)])
#define LD_B(N, KK) (*(const short8*)&Bc[brow + (N) * 1024 + (((KK) * 32 + klo) ^ cxor)])

    short8 af0[8], bf0[4], af1[8], bf1[4];
    // kk=0 fragments
    #pragma unroll
    for (int mt = 0; mt < 8; ++mt) af0[mt] = LD_A(mt, 0);
    #pragma unroll
    for (int nt = 0; nt < 4; ++nt) bf0[nt] = LD_B(nt, 0);
    // stage next A while kk=0 frags are in flight
    if (pf) {
      #pragma unroll
      for (int i = 0; i < 4; ++i) gload_lds16(srcA(kta, i), An + (i * 64 + wid * 8) * 64);
    }
    // kk=1 B fragments (LDS pipe keeps working under MFMA0)
    #pragma unroll
    for (int nt = 0; nt < 4; ++nt) bf1[nt] = LD_B(nt, 1);
    // MFMA cluster 0: 32 independent
    #pragma unroll
    for (int mt = 0; mt < 8; ++mt)
      #pragma unroll
      for (int nt = 0; nt < 4; ++nt)
        acc[mt][nt] = __builtin_amdgcn_mfma_f32_16x16x32_bf16(af0[mt], bf0[nt], acc[mt][nt], 0, 0, 0);
    // stage next B
    if (pf) {
      #pragma unroll
      for (int i = 0; i < 4; ++i) gload_lds16(srcB(kta, i), Bn + (i * 64 + wid * 8) * 64);
    }
    // kk=1 A fragments
    #pragma unroll
    for (int mt = 0; mt < 8; ++mt) af1[mt] = LD_A(mt, 1);
    // MFMA cluster 1: 32 independent
    #pragma unroll
    for (int mt = 0; mt < 8; ++mt)
      #pragma unroll
      for (int nt = 0; nt < 4; ++nt)
        acc[mt][nt] = __builtin_amdgcn_mfma_f32_16x16x32_bf16(af1[mt], bf1[nt], acc[mt][nt], 0, 0, 0);
    // boundary: __syncthreads waits vmcnt(0)+lgkmcnt(0) then barriers -> slot swap safe
    __syncthreads();
#undef LD_A
#undef LD_B
  }

  // -------- epilogue: C write --------
  #pragma unroll
  for (int mt = 0; mt < 8; ++mt) {
    #pragma unroll
    for (int j = 0; j < 4; ++j) {
      int co = wr * 128 + mt * 16 + ((lane >> 4) * 4) + j;
      float bv = bias[co];
      #pragma unroll
      for (int nt = 0; nt < 4; ++nt) {
        int px = wc * 64 + nt * 16 + (lane & 15);
        int h = h0 + (px >> 7), w = px & 127;
        out[(((size_t)b * COUT + co) * HW + h) * HW + w] = acc[mt][nt][j] + bv;
      }
    }
  }
}

extern "C" void kernel_launch(void* const* d_in, const int* in_sizes, int n_in,
                              void* d_out, int out_size, void* d_ws, size_t ws_size,
                              hipStream_t stream) {
  const float* x      = (const float*)d_in[0];
  const float* style  = (const float*)d_in[1];
  const float* weight = (const float*)d_in[2];
  const float* mod_w  = (const float*)d_in[3];
  const float* mod_b  = (const float*)d_in[4];
  const float* bias   = (const float*)d_in[5];
  float* out = (float*)d_out;

  char* ws = (char*)d_ws;
  float* s   = (float*)ws;                                           // 16 KB
  u16* Wb    = (u16*)(ws + 16384);                                   // 18.9 MB
  u16* xTp   = (u16*)(ws + 16384 + (size_t)NB * 9 * COUT * CIN * 2); // 138.4 MB

  (void)hipFuncSetAttribute((const void*)k_conv,
                            hipFuncAttributeMaxDynamicSharedMemorySize, 2 * SLOTU * 2);

  k_style<<<NB, 256, 0, stream>>>(style, mod_w, mod_b, s);
  k_wmod<<<NB * COUT, 256, 0, stream>>>(weight, s, Wb);
  k_xt<<<NB * HW, 256, 0, stream>>>(x, xTp);
  k_conv<<<NB * (HW / 2), 512, 2 * SLOTU * 2, stream>>>(Wb, xTp, bias, out);
}